// Round 5
// baseline (251.677 us; speedup 1.0000x reference)
//
#include <hip/hip_runtime.h>

typedef short bf16x8 __attribute__((ext_vector_type(8)));
typedef float f32x4  __attribute__((ext_vector_type(4)));
typedef unsigned short u16x4 __attribute__((ext_vector_type(4)));

#define BROW 584              // ushorts per co row in LDS B chunk (576 + 8 pad)
#define BBUF (16 * BROW)      // one chunk buffer: 16 co rows
#define LSTR 296              // fallback kernel LDS stride

__device__ __forceinline__ unsigned short f2bf(float f) {
    unsigned u = __float_as_uint(f);
    return (unsigned short)((u + 0x7FFFu + ((u >> 16) & 1u)) >> 16);  // RNE
}

// ---- Kernel 1: x[bc][hw] f32 -> xT[hw][bc] bf16 ----
__global__ __launch_bounds__(256)
void transpose_in(const float* __restrict__ x, unsigned short* __restrict__ xT) {
    __shared__ float tile[64][65];
    const int t  = threadIdx.x;
    const int tr = blockIdx.x >> 6, tc = blockIdx.x & 63;
    const int r0 = tr << 6, c0 = tc << 6;
    const int cc = (t & 15) << 2;
    #pragma unroll
    for (int q = 0; q < 4; ++q) {
        const int rr = (t >> 4) + (q << 4);
        const f32x4 v = __builtin_nontemporal_load(
            (const f32x4*)&x[(size_t)(r0 + rr) * 4096 + c0 + cc]);
        tile[rr][cc + 0] = v[0]; tile[rr][cc + 1] = v[1];
        tile[rr][cc + 2] = v[2]; tile[rr][cc + 3] = v[3];
    }
    __syncthreads();
    #pragma unroll
    for (int q = 0; q < 4; ++q) {
        const int rr = (t >> 4) + (q << 4);
        u16x4 o;
        o[0] = f2bf(tile[cc + 0][rr]); o[1] = f2bf(tile[cc + 1][rr]);
        o[2] = f2bf(tile[cc + 2][rr]); o[3] = f2bf(tile[cc + 3][rr]);
        *(u16x4*)&xT[(size_t)(c0 + rr) * 4096 + r0 + cc] = o;
    }
}

// ---- Kernel 3: outT[hw][bc] bf16 -> out[bc][hw] f32 ----
__global__ __launch_bounds__(256)
void transpose_out_bf(const unsigned short* __restrict__ src, float* __restrict__ dst) {
    __shared__ unsigned short tile[64][66];
    const int t  = threadIdx.x;
    const int tr = blockIdx.x >> 6, tc = blockIdx.x & 63;
    const int r0 = tr << 6, c0 = tc << 6;
    const int cc = (t & 15) << 2;
    #pragma unroll
    for (int q = 0; q < 4; ++q) {
        const int rr = (t >> 4) + (q << 4);
        const u16x4 v = __builtin_nontemporal_load(
            (const u16x4*)&src[(size_t)(r0 + rr) * 4096 + c0 + cc]);
        tile[rr][cc + 0] = v[0]; tile[rr][cc + 1] = v[1];
        tile[rr][cc + 2] = v[2]; tile[rr][cc + 3] = v[3];
    }
    __syncthreads();
    #pragma unroll
    for (int q = 0; q < 4; ++q) {
        const int rr = (t >> 4) + (q << 4);
        f32x4 o;
        o[0] = __uint_as_float((unsigned)tile[cc + 0][rr] << 16);
        o[1] = __uint_as_float((unsigned)tile[cc + 1][rr] << 16);
        o[2] = __uint_as_float((unsigned)tile[cc + 2][rr] << 16);
        o[3] = __uint_as_float((unsigned)tile[cc + 3][rr] << 16);
        __builtin_nontemporal_store(o, (f32x4*)&dst[(size_t)(c0 + rr) * 4096 + r0 + cc]);
    }
}

// ---- Kernel 2: main GEMM, one block per (h,w). k' = tap*64 + ci order. ----
// B (weights) read SEQUENTIALLY from global per wave, staged to LDS (bf16,
// k'-permuted, dbuf 16-co chunks). A read directly from xT (16B frags, L1/L2).
__global__ __launch_bounds__(256, 4)
void lc_main(const unsigned short* __restrict__ xT, const float* __restrict__ wt,
             unsigned short* __restrict__ outT) {
    __shared__ __align__(16) unsigned short Bs[2 * BBUF];   // 37376 B

    const int bid = blockIdx.x;
    const int swz = (bid & 7) * 512 + (bid >> 3);   // XCD-contiguous bijective remap
    const int h = swz >> 6, wq = swz & 63;

    const int t = threadIdx.x;
    const int lane = t & 63;
    const int wv  = t >> 6;          // wave id: stage slice AND m-tile
    const int l15 = lane & 15;
    const int kg  = lane >> 4;

    // sequential weight staging: wave wv owns floats [wv*2304 .. +2304) of each chunk
    const float* wchunk0 = wt + (size_t)((h << 6) + wq) * 36864 + wv * 2304 + lane * 4;

    // per-tap xT row base (safe row 0 when out of image) + validity
    int tapb[9]; int tval[9];
    #pragma unroll
    for (int tap = 0; tap < 9; ++tap) {
        const int y = h + tap / 3 - 1, xx = wq + tap % 3 - 1;
        const int ok = ((unsigned)y < 64u) && ((unsigned)xx < 64u);
        tval[tap] = ok;
        tapb[tap] = ok ? ((y << 6) + xx) : 0;
    }

    // A-frag base: row b = wv*16+l15, k-sub kg; per ks add tapb[ks>>1]*4096 + (ks&1)*32
    const unsigned short* aBase = xT + (((wv << 4) + l15) << 6) + (kg << 3);

    // precompute the 36 LDS scatter offsets (identical for all 4 chunks):
    // global float g (within chunk) -> (co, ci, tap) -> ushort co*BROW + tap*64 + ci
    unsigned short wa[36];
    {
        const int g0 = wv * 2304 + lane * 4;
        #pragma unroll
        for (int i = 0; i < 9; ++i) {
            const int g = g0 + i * 256;
            const int co = g / 576;
            const int r = g - co * 576;          // multiple of 4 -> j never crosses co
            #pragma unroll
            for (int j = 0; j < 4; ++j) {
                const int ci = (r + j) / 9;
                const int tap = (r + j) - ci * 9;
                wa[i * 4 + j] = (unsigned short)(co * BROW + tap * 64 + ci);
            }
        }
    }

    f32x4 sreg[9];
    const size_t obase = (size_t)((h << 6) + wq) * 4096;

    // prologue: stage chunk 0
    {
        const float* src = wchunk0;
        #pragma unroll
        for (int i = 0; i < 9; ++i)
            sreg[i] = __builtin_nontemporal_load((const f32x4*)(src + i * 256));
        #pragma unroll
        for (int i = 0; i < 9; ++i)
            #pragma unroll
            for (int j = 0; j < 4; ++j)
                Bs[wa[i * 4 + j]] = f2bf(sreg[i][j]);
    }

    #pragma unroll
    for (int q = 0; q < 4; ++q) {
        __syncthreads();
        const unsigned short* Bq = &Bs[(q & 1) * BBUF];

        // preload A ring (issued BEFORE next-chunk stage loads so no false vmcnt dep)
        bf16x8 af[4];
        #pragma unroll
        for (int p = 0; p < 4; ++p)
            af[p] = *(const bf16x8*)(aBase + (size_t)tapb[p >> 1] * 4096 + ((p & 1) << 5));

        // T14: issue next chunk's sequential weight loads early
        if (q < 3) {
            const float* src = wchunk0 + (q + 1) * 9216;
            #pragma unroll
            for (int i = 0; i < 9; ++i)
                sreg[i] = __builtin_nontemporal_load((const f32x4*)(src + i * 256));
        }

        f32x4 acc = {0.f, 0.f, 0.f, 0.f};
        #pragma unroll
        for (int ks = 0; ks < 18; ++ks) {
            const bf16x8 bf = *(const bf16x8*)&Bq[l15 * BROW + ks * 32 + (kg << 3)];
            if (tval[ks >> 1])   // block-uniform: skip out-of-image taps
                acc = __builtin_amdgcn_mfma_f32_16x16x32_bf16(af[ks & 3], bf, acc, 0, 0, 0);
            if (ks < 14)
                af[ks & 3] = *(const bf16x8*)(aBase
                    + (size_t)tapb[(ks + 4) >> 1] * 4096 + (((ks + 4) & 1) << 5));
        }

        // epilogue chunk q: co = q*16+l15, b = wv*16 + kg*4 + j
        #pragma unroll
        for (int j = 0; j < 4; ++j) {
            const int b = (wv << 4) + (kg << 2) + j;
            const unsigned short v = f2bf(fmaxf(acc[j], 0.f));
            __builtin_nontemporal_store(v, &outT[obase + (b << 6) + (q << 4) + l15]);
        }

        // write next chunk into the other LDS buffer (readers of it finished pre-barrier)
        if (q < 3) {
            unsigned short* dstb = &Bs[((q + 1) & 1) * BBUF];
            #pragma unroll
            for (int i = 0; i < 9; ++i)
                #pragma unroll
                for (int j = 0; j < 4; ++j)
                    dstb[wa[i * 4 + j]] = f2bf(sreg[i][j]);
        }
    }
}

// ---- Fallback (round-2 proven): direct gather + scattered write ----
__global__ __launch_bounds__(256, 4)
void lc_mfma(const float* __restrict__ x, const float* __restrict__ wt,
             float* __restrict__ out) {
    __shared__ __align__(16) unsigned short A[64 * LSTR];
    const int bid = blockIdx.x;
    const int swz = (bid & 7) * 512 + (bid >> 3);
    const int h   = swz >> 6;
    const int wq  = swz & 63;
    const int t    = threadIdx.x;
    const int lane = t & 63;
    const int wv   = t >> 6;
    const float* wloc = wt + (size_t)((h << 6) + wq) * 36864;
    const int co = (wv << 4) + (lane & 15);
    const int kg = lane >> 4;
    const float* wrow = wloc + co * 576 + (kg << 3);
    f32x4 acc[4] = {{0.f,0.f,0.f,0.f},{0.f,0.f,0.f,0.f},
                    {0.f,0.f,0.f,0.f},{0.f,0.f,0.f,0.f}};
    const int cil = t & 31;
    const int bro = t >> 5;
    for (int hs = 0; hs < 2; ++hs) {
        const int kbase = hs * 288;
        f32x4 pb[3][2];
        pb[0][0] = __builtin_nontemporal_load((const f32x4*)(wrow + kbase + 0));
        pb[0][1] = __builtin_nontemporal_load((const f32x4*)(wrow + kbase + 4));
        pb[1][0] = __builtin_nontemporal_load((const f32x4*)(wrow + kbase + 32));
        pb[1][1] = __builtin_nontemporal_load((const f32x4*)(wrow + kbase + 36));
        {
            const int ci = (hs << 5) + cil;
            for (int p = 0; p < 8; ++p) {
                const int b = (p << 3) + bro;
                const float* xb = x + ((size_t)((b << 6) + ci) << 12);
                unsigned short* dst = &A[b * LSTR + cil * 9];
                #pragma unroll
                for (int dy = 0; dy < 3; ++dy) {
                    const int y = h + dy - 1;
                    const bool yok = (unsigned)y < 64u;
                    #pragma unroll
                    for (int dx = 0; dx < 3; ++dx) {
                        const int xx = wq + dx - 1;
                        float v = 0.f;
                        if (yok && (unsigned)xx < 64u) v = xb[(y << 6) + xx];
                        dst[dy * 3 + dx] = f2bf(v);
                    }
                }
            }
        }
        __syncthreads();
        #pragma unroll
        for (int ks = 0; ks < 9; ++ks) {
            const int cur = ks % 3;
            const int nxt = (ks + 2) % 3;
            if (ks < 7) {
                const float* np = wrow + kbase + (ks + 2) * 32;
                pb[nxt][0] = __builtin_nontemporal_load((const f32x4*)(np));
                pb[nxt][1] = __builtin_nontemporal_load((const f32x4*)(np + 4));
            }
            const f32x4 lo = pb[cur][0], hi = pb[cur][1];
            bf16x8 bf;
            bf[0] = (short)f2bf(lo[0]); bf[1] = (short)f2bf(lo[1]);
            bf[2] = (short)f2bf(lo[2]); bf[3] = (short)f2bf(lo[3]);
            bf[4] = (short)f2bf(hi[0]); bf[5] = (short)f2bf(hi[1]);
            bf[6] = (short)f2bf(hi[2]); bf[7] = (short)f2bf(hi[3]);
            const int kk = (ks << 5) + (kg << 3);
            #pragma unroll
            for (int mt = 0; mt < 4; ++mt) {
                const bf16x8 afl = *(const bf16x8*)&A[((mt << 4) + (lane & 15)) * LSTR + kk];
                acc[mt] = __builtin_amdgcn_mfma_f32_16x16x32_bf16(afl, bf, acc[mt], 0, 0, 0);
            }
        }
        __syncthreads();
    }
    const int rg = lane >> 4;
    #pragma unroll
    for (int mt = 0; mt < 4; ++mt) {
        #pragma unroll
        for (int j = 0; j < 4; ++j) {
            const int b = (mt << 4) + (rg << 2) + j;
            out[(size_t)((b << 6) + co) * 4096 + (h << 6) + wq] = fmaxf(acc[mt][j], 0.f);
        }
    }
}

extern "C" void kernel_launch(void* const* d_in, const int* in_sizes, int n_in,
                              void* d_out, int out_size, void* d_ws, size_t ws_size,
                              hipStream_t stream) {
    const float* x  = (const float*)d_in[0];
    const float* wt = (const float*)d_in[1];
    float* out = (float*)d_out;

    const size_t xT_bytes   = (size_t)4096 * 4096 * 2;
    const size_t outT_bytes = (size_t)4096 * 4096 * 2;

    if (ws_size >= xT_bytes + outT_bytes) {
        unsigned short* xT   = (unsigned short*)d_ws;
        unsigned short* outT = (unsigned short*)((char*)d_ws + xT_bytes);
        hipLaunchKernelGGL(transpose_in, dim3(4096), dim3(256), 0, stream, x, xT);
        hipLaunchKernelGGL(lc_main, dim3(4096), dim3(256), 0, stream, xT, wt, outT);
        hipLaunchKernelGGL(transpose_out_bf, dim3(4096), dim3(256), 0, stream, outT, out);
    } else {
        hipLaunchKernelGGL(lc_mfma, dim3(4096), dim3(256), 0, stream, x, wt, out);
    }
}

// Round 6
// 206.445 us; speedup vs baseline: 1.2191x; 1.2191x over previous
//
#include <hip/hip_runtime.h>

typedef short bf16x8 __attribute__((ext_vector_type(8)));
typedef float f32x4  __attribute__((ext_vector_type(4)));
typedef unsigned short u16x4 __attribute__((ext_vector_type(4)));

#define LSTR 296  // LDS row stride in ushorts (288 data + 8 pad)

__device__ __forceinline__ unsigned short f2bf(float f) {
    unsigned u = __float_as_uint(f);
    return (unsigned short)((u + 0x7FFFu + ((u >> 16) & 1u)) >> 16);  // RNE
}

// ---- Kernel 1: x[bc][hw] f32 -> xT[hw][bc] bf16 ----
__global__ __launch_bounds__(256)
void transpose_in(const float* __restrict__ x, unsigned short* __restrict__ xT) {
    __shared__ float tile[64][65];
    const int t  = threadIdx.x;
    const int tr = blockIdx.x >> 6, tc = blockIdx.x & 63;
    const int r0 = tr << 6, c0 = tc << 6;
    const int cc = (t & 15) << 2;
    #pragma unroll
    for (int q = 0; q < 4; ++q) {
        const int rr = (t >> 4) + (q << 4);
        const f32x4 v = __builtin_nontemporal_load(
            (const f32x4*)&x[(size_t)(r0 + rr) * 4096 + c0 + cc]);
        tile[rr][cc + 0] = v[0]; tile[rr][cc + 1] = v[1];
        tile[rr][cc + 2] = v[2]; tile[rr][cc + 3] = v[3];
    }
    __syncthreads();
    #pragma unroll
    for (int q = 0; q < 4; ++q) {
        const int rr = (t >> 4) + (q << 4);
        u16x4 o;
        o[0] = f2bf(tile[cc + 0][rr]); o[1] = f2bf(tile[cc + 1][rr]);
        o[2] = f2bf(tile[cc + 2][rr]); o[3] = f2bf(tile[cc + 3][rr]);
        *(u16x4*)&xT[(size_t)(c0 + rr) * 4096 + r0 + cc] = o;
    }
}

// ---- Kernel 3: outT[hw][bc] bf16 -> out[bc][hw] f32 ----
__global__ __launch_bounds__(256)
void transpose_out_bf(const unsigned short* __restrict__ src, float* __restrict__ dst) {
    __shared__ unsigned short tile[64][66];
    const int t  = threadIdx.x;
    const int tr = blockIdx.x >> 6, tc = blockIdx.x & 63;
    const int r0 = tr << 6, c0 = tc << 6;
    const int cc = (t & 15) << 2;
    #pragma unroll
    for (int q = 0; q < 4; ++q) {
        const int rr = (t >> 4) + (q << 4);
        const u16x4 v = __builtin_nontemporal_load(
            (const u16x4*)&src[(size_t)(r0 + rr) * 4096 + c0 + cc]);
        tile[rr][cc + 0] = v[0]; tile[rr][cc + 1] = v[1];
        tile[rr][cc + 2] = v[2]; tile[rr][cc + 3] = v[3];
    }
    __syncthreads();
    #pragma unroll
    for (int q = 0; q < 4; ++q) {
        const int rr = (t >> 4) + (q << 4);
        f32x4 o;
        o[0] = __uint_as_float((unsigned)tile[cc + 0][rr] << 16);
        o[1] = __uint_as_float((unsigned)tile[cc + 1][rr] << 16);
        o[2] = __uint_as_float((unsigned)tile[cc + 2][rr] << 16);
        o[3] = __uint_as_float((unsigned)tile[cc + 3][rr] << 16);
        __builtin_nontemporal_store(o, (f32x4*)&dst[(size_t)(c0 + rr) * 4096 + r0 + cc]);
    }
}

// ---- Kernel 2: main GEMM (round-4 structure, 4-deep weight lookahead) ----
__global__ __launch_bounds__(256, 4)
void lc_main(const unsigned short* __restrict__ xT, const float* __restrict__ wt,
             unsigned short* __restrict__ outT) {
    __shared__ __align__(16) unsigned short A[64 * LSTR];

    const int bid = blockIdx.x;
    const int swz = (bid & 7) * 512 + (bid >> 3);   // XCD-contiguous bijective remap
    const int h   = swz >> 6;
    const int wq  = swz & 63;

    const int t    = threadIdx.x;
    const int lane = t & 63;
    const int wv   = t >> 6;

    const float* wloc = wt + (size_t)((h << 6) + wq) * 36864;
    const int co = (wv << 4) + (lane & 15);
    const int kg = lane >> 4;
    const float* wrow = wloc + co * 576 + (kg << 3);   // + ks*32 per step, ks 0..17

    f32x4 acc[4] = {{0.f,0.f,0.f,0.f},{0.f,0.f,0.f,0.f},
                    {0.f,0.f,0.f,0.f},{0.f,0.f,0.f,0.f}};

    const int b_st = t >> 2;   // staging: b 0..63
    const int cig  = t & 3;    // staging: 8-ci group

    // 4-deep weight lookahead: steps 0..3 issued FIRST (oldest in VMEM queue)
    f32x4 pb[4][2];
    #pragma unroll
    for (int p = 0; p < 4; ++p) {
        pb[p][0] = __builtin_nontemporal_load((const f32x4*)(wrow + p * 32));
        pb[p][1] = __builtin_nontemporal_load((const f32x4*)(wrow + p * 32 + 4));
    }

    // xT loads for half 0
    bf16x8 xr[9];
    #pragma unroll
    for (int tap = 0; tap < 9; ++tap) {
        const int y  = h + tap / 3 - 1;
        const int xx = wq + tap % 3 - 1;
        bf16x8 v = {0,0,0,0,0,0,0,0};
        if ((unsigned)y < 64u && (unsigned)xx < 64u)
            v = *(const bf16x8*)&xT[(size_t)((y << 6) + xx) * 4096 + (b_st << 6) + (cig << 3)];
        xr[tap] = v;
    }
    // write half 0 to LDS (k = ci*9+tap within half)
    {
        unsigned short* dst = &A[b_st * LSTR + cig * 72];
        #pragma unroll
        for (int tap = 0; tap < 9; ++tap)
            #pragma unroll
            for (int j = 0; j < 8; ++j)
                dst[j * 9 + tap] = (unsigned short)xr[tap][j];
    }
    // issue half 1 xT loads now — in flight across barrier + half0 MFMA (T14)
    #pragma unroll
    for (int tap = 0; tap < 9; ++tap) {
        const int y  = h + tap / 3 - 1;
        const int xx = wq + tap % 3 - 1;
        bf16x8 v = {0,0,0,0,0,0,0,0};
        if ((unsigned)y < 64u && (unsigned)xx < 64u)
            v = *(const bf16x8*)&xT[(size_t)((y << 6) + xx) * 4096 + (b_st << 6) + 32 + (cig << 3)];
        xr[tap] = v;
    }
    __syncthreads();

    // ---- 18 continuous k-steps of 32; LDS swap between step 8 and 9 ----
    #pragma unroll
    for (int ks = 0; ks < 18; ++ks) {
        if (ks == 9) {
            __syncthreads();   // all waves done reading half0
            unsigned short* dst = &A[b_st * LSTR + cig * 72];
            #pragma unroll
            for (int tap = 0; tap < 9; ++tap)
                #pragma unroll
                for (int j = 0; j < 8; ++j)
                    dst[j * 9 + tap] = (unsigned short)xr[tap][j];
            __syncthreads();
        }
        // consume slot ks&3, then refill it with step ks+4
        const f32x4 lo = pb[ks & 3][0], hi = pb[ks & 3][1];
        if (ks < 14) {
            const float* np = wrow + (ks + 4) * 32;
            pb[ks & 3][0] = __builtin_nontemporal_load((const f32x4*)(np));
            pb[ks & 3][1] = __builtin_nontemporal_load((const f32x4*)(np + 4));
        }
        bf16x8 bf;
        bf[0] = (short)f2bf(lo[0]); bf[1] = (short)f2bf(lo[1]);
        bf[2] = (short)f2bf(lo[2]); bf[3] = (short)f2bf(lo[3]);
        bf[4] = (short)f2bf(hi[0]); bf[5] = (short)f2bf(hi[1]);
        bf[6] = (short)f2bf(hi[2]); bf[7] = (short)f2bf(hi[3]);
        const int kk = (ks % 9) * 32 + (kg << 3);
        #pragma unroll
        for (int mt = 0; mt < 4; ++mt) {
            const bf16x8 af = *(const bf16x8*)&A[((mt << 4) + (lane & 15)) * LSTR + kk];
            acc[mt] = __builtin_amdgcn_mfma_f32_16x16x32_bf16(af, bf, acc[mt], 0, 0, 0);
        }
    }

    // epilogue: outT[hw][b*64+co] bf16, contiguous per block
    const int rg = lane >> 4;
    const size_t obase = (size_t)((h << 6) + wq) * 4096;
    #pragma unroll
    for (int mt = 0; mt < 4; ++mt) {
        #pragma unroll
        for (int j = 0; j < 4; ++j) {
            const int b = (mt << 4) + (rg << 2) + j;
            outT[obase + (b << 6) + co] = f2bf(fmaxf(acc[mt][j], 0.f));
        }
    }
}

// ---- Fallback (round-2 proven): direct gather + scattered write ----
__global__ __launch_bounds__(256, 4)
void lc_mfma(const float* __restrict__ x, const float* __restrict__ wt,
             float* __restrict__ out) {
    __shared__ __align__(16) unsigned short A[64 * LSTR];
    const int bid = blockIdx.x;
    const int swz = (bid & 7) * 512 + (bid >> 3);
    const int h   = swz >> 6;
    const int wq  = swz & 63;
    const int t    = threadIdx.x;
    const int lane = t & 63;
    const int wv   = t >> 6;
    const float* wloc = wt + (size_t)((h << 6) + wq) * 36864;
    const int co = (wv << 4) + (lane & 15);
    const int kg = lane >> 4;
    const float* wrow = wloc + co * 576 + (kg << 3);
    f32x4 acc[4] = {{0.f,0.f,0.f,0.f},{0.f,0.f,0.f,0.f},
                    {0.f,0.f,0.f,0.f},{0.f,0.f,0.f,0.f}};
    const int cil = t & 31;
    const int bro = t >> 5;
    for (int hs = 0; hs < 2; ++hs) {
        const int kbase = hs * 288;
        f32x4 pb[3][2];
        pb[0][0] = __builtin_nontemporal_load((const f32x4*)(wrow + kbase + 0));
        pb[0][1] = __builtin_nontemporal_load((const f32x4*)(wrow + kbase + 4));
        pb[1][0] = __builtin_nontemporal_load((const f32x4*)(wrow + kbase + 32));
        pb[1][1] = __builtin_nontemporal_load((const f32x4*)(wrow + kbase + 36));
        {
            const int ci = (hs << 5) + cil;
            for (int p = 0; p < 8; ++p) {
                const int b = (p << 3) + bro;
                const float* xb = x + ((size_t)((b << 6) + ci) << 12);
                unsigned short* dst = &A[b * LSTR + cil * 9];
                #pragma unroll
                for (int dy = 0; dy < 3; ++dy) {
                    const int y = h + dy - 1;
                    const bool yok = (unsigned)y < 64u;
                    #pragma unroll
                    for (int dx = 0; dx < 3; ++dx) {
                        const int xx = wq + dx - 1;
                        float v = 0.f;
                        if (yok && (unsigned)xx < 64u) v = xb[(y << 6) + xx];
                        dst[dy * 3 + dx] = f2bf(v);
                    }
                }
            }
        }
        __syncthreads();
        #pragma unroll
        for (int ks = 0; ks < 9; ++ks) {
            const int cur = ks % 3;
            const int nxt = (ks + 2) % 3;
            if (ks < 7) {
                const float* np = wrow + kbase + (ks + 2) * 32;
                pb[nxt][0] = __builtin_nontemporal_load((const f32x4*)(np));
                pb[nxt][1] = __builtin_nontemporal_load((const f32x4*)(np + 4));
            }
            const f32x4 lo = pb[cur][0], hi = pb[cur][1];
            bf16x8 bf;
            bf[0] = (short)f2bf(lo[0]); bf[1] = (short)f2bf(lo[1]);
            bf[2] = (short)f2bf(lo[2]); bf[3] = (short)f2bf(lo[3]);
            bf[4] = (short)f2bf(hi[0]); bf[5] = (short)f2bf(hi[1]);
            bf[6] = (short)f2bf(hi[2]); bf[7] = (short)f2bf(hi[3]);
            const int kk = (ks << 5) + (kg << 3);
            #pragma unroll
            for (int mt = 0; mt < 4; ++mt) {
                const bf16x8 afl = *(const bf16x8*)&A[((mt << 4) + (lane & 15)) * LSTR + kk];
                acc[mt] = __builtin_amdgcn_mfma_f32_16x16x32_bf16(afl, bf, acc[mt], 0, 0, 0);
            }
        }
        __syncthreads();
    }
    const int rg = lane >> 4;
    #pragma unroll
    for (int mt = 0; mt < 4; ++mt) {
        #pragma unroll
        for (int j = 0; j < 4; ++j) {
            const int b = (mt << 4) + (rg << 2) + j;
            out[(size_t)((b << 6) + co) * 4096 + (h << 6) + wq] = fmaxf(acc[mt][j], 0.f);
        }
    }
}

extern "C" void kernel_launch(void* const* d_in, const int* in_sizes, int n_in,
                              void* d_out, int out_size, void* d_ws, size_t ws_size,
                              hipStream_t stream) {
    const float* x  = (const float*)d_in[0];
    const float* wt = (const float*)d_in[1];
    float* out = (float*)d_out;

    const size_t xT_bytes   = (size_t)4096 * 4096 * 2;
    const size_t outT_bytes = (size_t)4096 * 4096 * 2;

    if (ws_size >= xT_bytes + outT_bytes) {
        unsigned short* xT   = (unsigned short*)d_ws;
        unsigned short* outT = (unsigned short*)((char*)d_ws + xT_bytes);
        hipLaunchKernelGGL(transpose_in, dim3(4096), dim3(256), 0, stream, x, xT);
        hipLaunchKernelGGL(lc_main, dim3(4096), dim3(256), 0, stream, xT, wt, outT);
        hipLaunchKernelGGL(transpose_out_bf, dim3(4096), dim3(256), 0, stream, outT, out);
    } else {
        hipLaunchKernelGGL(lc_mfma, dim3(4096), dim3(256), 0, stream, x, wt, out);
    }
}

// Round 7
// 162.366 us; speedup vs baseline: 1.5501x; 1.2715x over previous
//
#include <hip/hip_runtime.h>

typedef short bf16x8 __attribute__((ext_vector_type(8)));
typedef float f32x4  __attribute__((ext_vector_type(4)));
typedef unsigned short u16x4 __attribute__((ext_vector_type(4)));

#define ASTR 296   // A row stride (ushorts): 288 + 8 pad
#define BSTR 296   // B row stride (ushorts): 288 + 8 pad
#define LSTR 296   // fallback kernel

__device__ __forceinline__ unsigned short f2bf(float f) {
    unsigned u = __float_as_uint(f);
    return (unsigned short)((u + 0x7FFFu + ((u >> 16) & 1u)) >> 16);  // RNE
}

// ---- Kernel 1: x[bc][hw] f32 -> xT[hw][bc] bf16 ----
__global__ __launch_bounds__(256)
void transpose_in(const float* __restrict__ x, unsigned short* __restrict__ xT) {
    __shared__ float tile[64][65];
    const int t  = threadIdx.x;
    const int tr = blockIdx.x >> 6, tc = blockIdx.x & 63;
    const int r0 = tr << 6, c0 = tc << 6;
    const int cc = (t & 15) << 2;
    #pragma unroll
    for (int q = 0; q < 4; ++q) {
        const int rr = (t >> 4) + (q << 4);
        const f32x4 v = __builtin_nontemporal_load(
            (const f32x4*)&x[(size_t)(r0 + rr) * 4096 + c0 + cc]);
        tile[rr][cc + 0] = v[0]; tile[rr][cc + 1] = v[1];
        tile[rr][cc + 2] = v[2]; tile[rr][cc + 3] = v[3];
    }
    __syncthreads();
    #pragma unroll
    for (int q = 0; q < 4; ++q) {
        const int rr = (t >> 4) + (q << 4);
        u16x4 o;
        o[0] = f2bf(tile[cc + 0][rr]); o[1] = f2bf(tile[cc + 1][rr]);
        o[2] = f2bf(tile[cc + 2][rr]); o[3] = f2bf(tile[cc + 3][rr]);
        *(u16x4*)&xT[(size_t)(c0 + rr) * 4096 + r0 + cc] = o;
    }
}

// ---- Kernel 3: outT[hw][bc] bf16 -> out[bc][hw] f32 ----
__global__ __launch_bounds__(256)
void transpose_out_bf(const unsigned short* __restrict__ src, float* __restrict__ dst) {
    __shared__ unsigned short tile[64][66];
    const int t  = threadIdx.x;
    const int tr = blockIdx.x >> 6, tc = blockIdx.x & 63;
    const int r0 = tr << 6, c0 = tc << 6;
    const int cc = (t & 15) << 2;
    #pragma unroll
    for (int q = 0; q < 4; ++q) {
        const int rr = (t >> 4) + (q << 4);
        const u16x4 v = __builtin_nontemporal_load(
            (const u16x4*)&src[(size_t)(r0 + rr) * 4096 + c0 + cc]);
        tile[rr][cc + 0] = v[0]; tile[rr][cc + 1] = v[1];
        tile[rr][cc + 2] = v[2]; tile[rr][cc + 3] = v[3];
    }
    __syncthreads();
    #pragma unroll
    for (int q = 0; q < 4; ++q) {
        const int rr = (t >> 4) + (q << 4);
        f32x4 o;
        o[0] = __uint_as_float((unsigned)tile[cc + 0][rr] << 16);
        o[1] = __uint_as_float((unsigned)tile[cc + 1][rr] << 16);
        o[2] = __uint_as_float((unsigned)tile[cc + 2][rr] << 16);
        o[3] = __uint_as_float((unsigned)tile[cc + 3][rr] << 16);
        __builtin_nontemporal_store(o, (f32x4*)&dst[(size_t)(c0 + rr) * 4096 + r0 + cc]);
    }
}

// ---- Kernel 2: main GEMM. B staged through LDS with SEQUENTIAL weight reads. ----
// Per block (h,w): A[64 b][288 k] per k-half (round-4 proven layout) +
// B chunk [32 co][288 k], staged as identity copy (1152 B sequential runs/row).
// Waves: wv>>1 -> m-half (32 b), wv&1 -> n-tile within co-half. acc[2 m][2 ch].
__global__ __launch_bounds__(256, 2)
void lc_main(const unsigned short* __restrict__ xT, const float* __restrict__ wt,
             unsigned short* __restrict__ outT) {
    __shared__ __align__(16) unsigned short A[64 * ASTR];   // 37888 B
    __shared__ __align__(16) unsigned short B[32 * BSTR];   // 18944 B

    const int bid = blockIdx.x;
    const int swz = (bid & 7) * 512 + (bid >> 3);   // bijective XCD remap
    const int h = swz >> 6, wq = swz & 63;
    const int loc = (h << 6) + wq;

    const int t    = threadIdx.x;
    const int lane = t & 63;
    const int wv   = t >> 6;
    const int l15  = lane & 15;
    const int kg   = lane >> 4;

    const float* wloc = wt + (size_t)loc * 36864;

    // B staging map: thread t -> chunk row bco (0..31), granule oct (0..7)
    const int bco = t >> 3;
    const int oct = t & 7;

    // A staging map (round-4): b_st (0..63), cig (0..3)
    const int b_st = t >> 2;
    const int cig  = t & 3;

    // taps
    int tapr[9]; int tv[9];
    #pragma unroll
    for (int tap = 0; tap < 9; ++tap) {
        const int y = h + tap / 3 - 1, xx = wq + tap % 3 - 1;
        const int ok = ((unsigned)y < 64u) && ((unsigned)xx < 64u);
        tv[tap] = ok;
        tapr[tap] = ok ? ((y << 6) + xx) : 0;
    }

    f32x4 acc[2][2] = {{{0.f,0.f,0.f,0.f},{0.f,0.f,0.f,0.f}},
                       {{0.f,0.f,0.f,0.f},{0.f,0.f,0.f,0.f}}};
    f32x4  br[9];
    bf16x8 xr[9];

    auto issueB = [&](int hs, int ch) {
        const float* s = wloc + (size_t)(ch * 32 + bco) * 576 + hs * 288 + (oct << 2);
        #pragma unroll
        for (int i = 0; i < 9; ++i)
            br[i] = __builtin_nontemporal_load((const f32x4*)(s + (i << 5)));
    };
    auto writeB = [&]() {
        unsigned short* d = &B[bco * BSTR + (oct << 2)];
        #pragma unroll
        for (int i = 0; i < 9; ++i) {
            u16x4 o;
            o[0] = f2bf(br[i][0]); o[1] = f2bf(br[i][1]);
            o[2] = f2bf(br[i][2]); o[3] = f2bf(br[i][3]);
            *(u16x4*)&d[i << 5] = o;
        }
    };
    auto issueA = [&](int hs) {
        #pragma unroll
        for (int tap = 0; tap < 9; ++tap) {
            bf16x8 v = {0,0,0,0,0,0,0,0};
            if (tv[tap])
                v = *(const bf16x8*)&xT[(size_t)tapr[tap] * 4096 + (b_st << 6)
                                        + hs * 32 + (cig << 3)];
            xr[tap] = v;
        }
    };
    auto writeA = [&]() {
        unsigned short* d = &A[b_st * ASTR + cig * 72];
        #pragma unroll
        for (int tap = 0; tap < 9; ++tap)
            #pragma unroll
            for (int j = 0; j < 8; ++j)
                d[j * 9 + tap] = (unsigned short)xr[tap][j];
    };
    auto compute = [&](int ch) {
        const int arow0 = ((wv >> 1) * 32 + l15) * ASTR + (kg << 3);
        const int brow  = ((wv & 1) * 16 + l15) * BSTR + (kg << 3);
        #pragma unroll
        for (int ksl = 0; ksl < 9; ++ksl) {
            const int kk = ksl * 32;
            const bf16x8 bfr = *(const bf16x8*)&B[brow + kk];
            const bf16x8 a0  = *(const bf16x8*)&A[arow0 + kk];
            const bf16x8 a1  = *(const bf16x8*)&A[arow0 + 16 * ASTR + kk];
            acc[0][ch] = __builtin_amdgcn_mfma_f32_16x16x32_bf16(a0, bfr, acc[0][ch], 0, 0, 0);
            acc[1][ch] = __builtin_amdgcn_mfma_f32_16x16x32_bf16(a1, bfr, acc[1][ch], 0, 0, 0);
        }
    };

    // ---- T14 pipeline: issue one phase ahead of every LDS-write phase ----
    issueB(0, 0); issueA(0);
    writeB(); writeA();
    issueB(0, 1);
    __syncthreads();
    compute(0);                       // (hs0, ch0); B01 in flight
    __syncthreads();
    writeB(); issueB(1, 0); issueA(1);
    __syncthreads();
    compute(1);                       // (hs0, ch1); B10+A1 in flight
    __syncthreads();
    writeB(); writeA();
    issueB(1, 1);
    __syncthreads();
    compute(0);                       // (hs1, ch0); B11 in flight
    __syncthreads();
    writeB();
    __syncthreads();
    compute(1);                       // (hs1, ch1)

    // epilogue: outT[hw][b*64+co] bf16
    const size_t obase = (size_t)loc * 4096;
    #pragma unroll
    for (int m2 = 0; m2 < 2; ++m2)
        #pragma unroll
        for (int ch = 0; ch < 2; ++ch)
            #pragma unroll
            for (int j = 0; j < 4; ++j) {
                const int b  = (wv >> 1) * 32 + m2 * 16 + (kg << 2) + j;
                const int co = ch * 32 + (wv & 1) * 16 + l15;
                outT[obase + (b << 6) + co] = f2bf(fmaxf(acc[m2][ch][j], 0.f));
            }
}

// ---- Fallback (round-2 proven): direct gather + scattered write ----
__global__ __launch_bounds__(256, 4)
void lc_mfma(const float* __restrict__ x, const float* __restrict__ wt,
             float* __restrict__ out) {
    __shared__ __align__(16) unsigned short A[64 * LSTR];
    const int bid = blockIdx.x;
    const int swz = (bid & 7) * 512 + (bid >> 3);
    const int h   = swz >> 6;
    const int wq  = swz & 63;
    const int t    = threadIdx.x;
    const int lane = t & 63;
    const int wv   = t >> 6;
    const float* wloc = wt + (size_t)((h << 6) + wq) * 36864;
    const int co = (wv << 4) + (lane & 15);
    const int kg = lane >> 4;
    const float* wrow = wloc + co * 576 + (kg << 3);
    f32x4 acc[4] = {{0.f,0.f,0.f,0.f},{0.f,0.f,0.f,0.f},
                    {0.f,0.f,0.f,0.f},{0.f,0.f,0.f,0.f}};
    const int cil = t & 31;
    const int bro = t >> 5;
    for (int hs = 0; hs < 2; ++hs) {
        const int kbase = hs * 288;
        f32x4 pb[3][2];
        pb[0][0] = __builtin_nontemporal_load((const f32x4*)(wrow + kbase + 0));
        pb[0][1] = __builtin_nontemporal_load((const f32x4*)(wrow + kbase + 4));
        pb[1][0] = __builtin_nontemporal_load((const f32x4*)(wrow + kbase + 32));
        pb[1][1] = __builtin_nontemporal_load((const f32x4*)(wrow + kbase + 36));
        {
            const int ci = (hs << 5) + cil;
            for (int p = 0; p < 8; ++p) {
                const int b = (p << 3) + bro;
                const float* xb = x + ((size_t)((b << 6) + ci) << 12);
                unsigned short* dst = &A[b * LSTR + cil * 9];
                #pragma unroll
                for (int dy = 0; dy < 3; ++dy) {
                    const int y = h + dy - 1;
                    const bool yok = (unsigned)y < 64u;
                    #pragma unroll
                    for (int dx = 0; dx < 3; ++dx) {
                        const int xx = wq + dx - 1;
                        float v = 0.f;
                        if (yok && (unsigned)xx < 64u) v = xb[(y << 6) + xx];
                        dst[dy * 3 + dx] = f2bf(v);
                    }
                }
            }
        }
        __syncthreads();
        #pragma unroll
        for (int ks = 0; ks < 9; ++ks) {
            const int cur = ks % 3;
            const int nxt = (ks + 2) % 3;
            if (ks < 7) {
                const float* np = wrow + kbase + (ks + 2) * 32;
                pb[nxt][0] = __builtin_nontemporal_load((const f32x4*)(np));
                pb[nxt][1] = __builtin_nontemporal_load((const f32x4*)(np + 4));
            }
            const f32x4 lo = pb[cur][0], hi = pb[cur][1];
            bf16x8 bf;
            bf[0] = (short)f2bf(lo[0]); bf[1] = (short)f2bf(lo[1]);
            bf[2] = (short)f2bf(lo[2]); bf[3] = (short)f2bf(lo[3]);
            bf[4] = (short)f2bf(hi[0]); bf[5] = (short)f2bf(hi[1]);
            bf[6] = (short)f2bf(hi[2]); bf[7] = (short)f2bf(hi[3]);
            const int kk = (ks << 5) + (kg << 3);
            #pragma unroll
            for (int mt = 0; mt < 4; ++mt) {
                const bf16x8 afl = *(const bf16x8*)&A[((mt << 4) + (lane & 15)) * LSTR + kk];
                acc[mt] = __builtin_amdgcn_mfma_f32_16x16x32_bf16(afl, bf, acc[mt], 0, 0, 0);
            }
        }
        __syncthreads();
    }
    const int rg = lane >> 4;
    #pragma unroll
    for (int mt = 0; mt < 4; ++mt) {
        #pragma unroll
        for (int j = 0; j < 4; ++j) {
            const int b = (mt << 4) + (rg << 2) + j;
            out[(size_t)((b << 6) + co) * 4096 + (h << 6) + wq] = fmaxf(acc[mt][j], 0.f);
        }
    }
}

extern "C" void kernel_launch(void* const* d_in, const int* in_sizes, int n_in,
                              void* d_out, int out_size, void* d_ws, size_t ws_size,
                              hipStream_t stream) {
    const float* x  = (const float*)d_in[0];
    const float* wt = (const float*)d_in[1];
    float* out = (float*)d_out;

    const size_t xT_bytes   = (size_t)4096 * 4096 * 2;
    const size_t outT_bytes = (size_t)4096 * 4096 * 2;

    if (ws_size >= xT_bytes + outT_bytes) {
        unsigned short* xT   = (unsigned short*)d_ws;
        unsigned short* outT = (unsigned short*)((char*)d_ws + xT_bytes);
        hipLaunchKernelGGL(transpose_in, dim3(4096), dim3(256), 0, stream, x, xT);
        hipLaunchKernelGGL(lc_main, dim3(4096), dim3(256), 0, stream, xT, wt, outT);
        hipLaunchKernelGGL(transpose_out_bf, dim3(4096), dim3(256), 0, stream, outT, out);
    } else {
        hipLaunchKernelGGL(lc_mfma, dim3(4096), dim3(256), 0, stream, x, wt, out);
    }
}